// Round 8
// baseline (96.933 us; speedup 1.0000x reference)
//
#include <hip/hip_runtime.h>
#include <math.h>

// Shapes from reference: B=4, N=256, D=128, M=128, C=128
#define BB 4
#define NN 256
#define DD 128
#define MM 128
#define CC 128
#define ROWS (BB * NN)     // 1024
#define RPB 4              // rows per block
#define NBLK (ROWS / RPB)  // 256 blocks (== CU count, 1 block/CU)
#define TPB 512            // 8 waves

#define L2E 1.44269504088896340736f

typedef float f2 __attribute__((ext_vector_type(2)));

// Workspace float offsets
#define WS_PIB   0          // pibias [1024][128]
#define WS_PJLO  131072     // pjT lo-half [4][128 m][128 j<128] (pre-swizzled)
#define WS_PJHI  196608     // pjT hi-half [4][128 m][128 j>=128]
#define WS_W2T   262144     // W2^T  [128][128] (pre-swizzled)
#define WS_WC1T  278528     // Wc1^T
#define WS_WC2T  294912     // Wc2^T

static __device__ __forceinline__ float fast_exp2(float x) {
#if __has_builtin(__builtin_amdgcn_exp2f)
    return __builtin_amdgcn_exp2f(x);
#else
    return __exp2f(x);
#endif
}

static __device__ __forceinline__ float fast_rcp(float x) {
#if __has_builtin(__builtin_amdgcn_rcpf)
    return __builtin_amdgcn_rcpf(x);
#else
    return 1.0f / x;
#endif
}

// silu(x) = x / (1 + exp(-x))
static __device__ __forceinline__ float silu_f(float x) {
    float e = fast_exp2(-L2E * x);
    return x * fast_rcp(1.0f + e);
}

#if __has_builtin(__builtin_amdgcn_global_load_lds)
#define HAS_GLDS 1
#define GLDS(gp, lp)                                                        \
    __builtin_amdgcn_global_load_lds(                                       \
        (const __attribute__((address_space(1))) void*)(gp),                \
        (__attribute__((address_space(3))) void*)(lp), 16, 0, 0)
#else
#define HAS_GLDS 0
#endif

// Linear burst stage: ITERS * 8 waves * 1KB chunks (source already laid out /
// pre-swizzled in global; LDS image == byte copy of source).
template <int ITERS>
static __device__ __forceinline__ void stage_lin(float* lds, const float* g,
                                                 int t) {
#if HAS_GLDS
    const int wv = t >> 6, lane = t & 63;
    #pragma unroll
    for (int i = 0; i < ITERS; ++i) {
        const int c = i * 8 + wv;              // 256-float chunk id
        GLDS(g + (size_t)c * 256 + lane * 4, lds + c * 256);
    }
#else
    #pragma unroll
    for (int i = 0; i < ITERS; ++i)
        ((float4*)lds)[i * TPB + t] = ((const float4*)g)[i * TPB + t];
#endif
}

// ---------------------------------------------------------------------------
// Kernel A: pibias = h@W1a + b1 ; pjT = (h@W1b)^T (pre-swizzled scatter).
// NO weight LDS: thread (m = t&127, X = mat, dup = d-half) reads each W value
// exactly once per CU via coalesced global b32 (L2-resident), accumulates
// partials for ALL 4 rows against broadcast h (2 KB LDS), then combines the
// two d-halves through a 20 KB sRed buffer. Blocks 0-11 also transpose
// W2/Wc1/Wc2 (pre-swizzled) into workspace for k_msgout Phase B.
// ---------------------------------------------------------------------------
__global__ __launch_bounds__(TPB) void k_proj(const float* __restrict__ h,
                                              const float* __restrict__ W1a,
                                              const float* __restrict__ W1b,
                                              const float* __restrict__ b1,
                                              const float* __restrict__ W2,
                                              const float* __restrict__ Wc1,
                                              const float* __restrict__ Wc2,
                                              float* __restrict__ ws) {
    __shared__ __align__(16) float sH[RPB * DD];   // 2 KB
    __shared__ __align__(16) float sRed[256 * 20]; // 20 KB: (X,m) rows of 20

    const int t = threadIdx.x;
    const int m   = t & 127;
    const int X   = (t >> 7) & 1;   // 0: W1a, 1: W1b   (wave-uniform)
    const int dup = t >> 8;         // d-half            (wave-uniform)
    const int row0 = blockIdx.x * RPB;

    sH[t] = h[(size_t)row0 * DD + t];
    const float* __restrict__ Wp = X ? W1b : W1a;
    const float bias = b1[m];
    __syncthreads();                 // sH visible

    const int d0 = dup * 64;
    float a0 = 0.f, a1 = 0.f, a2 = 0.f, a3 = 0.f;
    #pragma unroll 4
    for (int c = 0; c < 16; ++c) {
        const int d = d0 + c * 4;
        // coalesced global loads (L2-hit after first touch), 1 per value/CU
        const float w0 = Wp[(size_t)(d + 0) * MM + m];
        const float w1 = Wp[(size_t)(d + 1) * MM + m];
        const float w2 = Wp[(size_t)(d + 2) * MM + m];
        const float w3 = Wp[(size_t)(d + 3) * MM + m];
        // broadcast h chunks for all 4 rows (wave-uniform b128)
        const float4 h0 = *(const float4*)&sH[0 * DD + d];
        const float4 h1 = *(const float4*)&sH[1 * DD + d];
        const float4 h2 = *(const float4*)&sH[2 * DD + d];
        const float4 h3 = *(const float4*)&sH[3 * DD + d];
        a0 = fmaf(h0.x, w0, a0); a0 = fmaf(h0.y, w1, a0);
        a0 = fmaf(h0.z, w2, a0); a0 = fmaf(h0.w, w3, a0);
        a1 = fmaf(h1.x, w0, a1); a1 = fmaf(h1.y, w1, a1);
        a1 = fmaf(h1.z, w2, a1); a1 = fmaf(h1.w, w3, a1);
        a2 = fmaf(h2.x, w0, a2); a2 = fmaf(h2.y, w1, a2);
        a2 = fmaf(h2.z, w2, a2); a2 = fmaf(h2.w, w3, a2);
        a3 = fmaf(h3.x, w0, a3); a3 = fmaf(h3.y, w1, a3);
        a3 = fmaf(h3.z, w2, a3); a3 = fmaf(h3.w, w3, a3);
    }
    {
        float4 pv; pv.x = a0; pv.y = a1; pv.z = a2; pv.w = a3;
        *(float4*)&sRed[((X << 7) | m) * 20 + dup * 8] = pv;  // 16B-aligned
    }
    __syncthreads();                 // partials visible

    // Combine: this thread finishes rows q = 2*dup, 2*dup+1 for its (X,m).
    {
        const int base = ((X << 7) | m) * 20;
        #pragma unroll
        for (int k = 0; k < 2; ++k) {
            const int q = 2 * dup + k;
            const float v = sRed[base + q] + sRed[base + 8 + q];
            if (X == 0) {            // wave-uniform branch
                ws[WS_PIB + (size_t)(row0 + q) * MM + m] = v + bias;
            } else {
                // pjT pre-swizzled scatter: pjT[m][jloc], 16B slot ^= (m&7)
                const int b    = row0 >> 8;
                const int jloc = (row0 & 255) + q;
                const int half = jloc >> 7;
                const int jj   = jloc & 127;
                const int c16  = jj >> 2;
                const int off  = (half ? WS_PJHI : WS_PJLO) + b * 16384 +
                                 m * 128 + (((c16 ^ (m & 7)) << 2) | (jj & 3));
                ws[off] = v;
            }
        }
    }

    // Weight transposes (pre-swizzled): blocks 0-11, 32 d-rows each.
    if (blockIdx.x < 12) {
        const int blk = blockIdx.x;
        const int qq = t >> 7;       // 0..3
        const float* Wsrc = (blk < 4) ? W2 : (blk < 8) ? Wc1 : Wc2;
        float* Wdst = ws + ((blk < 4) ? WS_W2T : (blk < 8) ? WS_WC1T : WS_WC2T);
        const int d0t = (blk & 3) * 32;
        const int k = m;
        #pragma unroll
        for (int i = 0; i < 8; ++i) {
            const int d = d0t + (qq << 3) + i;
            const float v = Wsrc[(size_t)d * 128 + k];   // coalesced over k
            Wdst[k * 128 + ((((d >> 2) ^ (k & 7)) << 2) | (d & 3))] = v;
        }
    }
}

// ---------------------------------------------------------------------------
// Kernel B: fused msg + output head. 256 blocks x 512 threads, 4 rows/block.
// Phase A: swizzled b128 pjT rows + uniform adj; packed-f32 (v_pk_*) pair
// math + ONE v_rcp per 4 silus (trans 6->5, VALU ~26->~17 per 4 elems) with
// two independent f2 accumulators (keeps round-7's dependency fix).
// Phase B partial-split: thread (q,m) reads only WT[m][32q..32q+32) (8 b128,
// each weight value once per CU), partials for ALL 4 rows, combine via sP.
// ---------------------------------------------------------------------------
__global__ __launch_bounds__(TPB) void k_msgout(const float* __restrict__ adj,
                                                const float* __restrict__ b2,
                                                const float* __restrict__ bc1,
                                                const float* __restrict__ bc2,
                                                const float* __restrict__ ws,
                                                float* __restrict__ out) {
    __shared__ __align__(16) float sLo[16384];    // 64 KB: pjT lo / W2T / Wc2T
    __shared__ __align__(16) float sHi[16384];    // 64 KB: pjT hi / Wc1T
    __shared__ __align__(16) float sS[RPB * MM];  // S rows, later t1
    __shared__ __align__(16) float sB[RPB * MM];  // magg
    __shared__ __align__(16) float sP[128 * 20];  // 10 KB: stage partials
    __shared__ float sWr0[8], sWr1[8];

    const int t = threadIdx.x;
    const int blk = blockIdx.x;        // 256 blocks
    const int b = blk >> 6;            // batch
    const int i0 = (blk & 63) * RPB;   // first row (batch-local)
    const int row0 = b * NN + i0;

    const int m = t & 127;
    const int q = t >> 7;              // row within block (uniform per wave)
    const int w = t >> 6;              // wave id
    const int swz = m & 7;

    // ---- issue pjT staging (128 KB total, pre-swizzled source -> linear)
    stage_lin<8>(sLo, ws + WS_PJLO + b * 16384, t);
    stage_lin<8>(sHi, ws + WS_PJHI + b * 16384, t);

    // ---- early loads (overlap with staging)
    const float pim  = ws[WS_PIB + (size_t)row0 * MM + t];  // pibias[row0+q][m]
    const float b2k  = b2[m];
    const float bc1k = bc1[m];
    const float bc2k = bc2[m];

    // adj row sums via coalesced vector loads + wave shuffle
    const float* arow = adj + (size_t)row0 * NN;
    const float a0v = arow[t];          // rows 0/1
    const float a1v = arow[t + TPB];    // rows 2/3
    float v0 = a0v, v1 = a1v;
    #pragma unroll
    for (int off = 32; off > 0; off >>= 1) {
        v0 += __shfl_xor(v0, off, 64);
        v1 += __shfl_xor(v1, off, 64);
    }
    if ((t & 63) == 0) { sWr0[w] = v0; sWr1[w] = v1; }

    // wave-uniform adj row pointer (scalarized)
    const int srow = __builtin_amdgcn_readfirstlane(row0 + q);
    const float* __restrict__ adjr = adj + (size_t)srow * NN;

    __syncthreads();   // B1: pjT staged, sWr visible

    float A;
    {
        const int base = (q & 1) * 4;
        A = (q < 2) ? (sWr0[base] + sWr0[base + 1] + sWr0[base + 2] + sWr0[base + 3])
                    : (sWr1[base] + sWr1[base + 1] + sWr1[base + 2] + sWr1[base + 3]);
    }
    const float aii = adjr[srow & 255];     // diagonal (uniform scalar load)
    const float inv = 1.0f / fmaxf(A, 1.0f);
    const float bet = (A - aii) * inv;
    const float npim = -L2E * pim;

    // Diagonal correction (subtract instead of zeroing adj)
    float dcorr;
    {
        const int iloc = i0 + q;
        const int jj = iloc & 127;
        const float* base = (iloc < 128) ? sLo : sHi;
        const float pjd = base[m * 128 + ((((jj >> 2) ^ swz) << 2) | (jj & 3))];
        dcorr = -aii * silu_f(pim + pjd);
    }

    // ---- Phase A: packed-f32 pair math, 4 silus per v_rcp,
    //      two independent f2 accumulators.
    const f2 pim2  = {pim, pim};
    const f2 npim2 = {npim, npim};
    const f2 nl2e2 = {-L2E, -L2E};
    f2 acc01 = {dcorr, 0.0f};
    f2 acc23 = {0.0f, 0.0f};

    // j in [0,128): swizzled b128 rows of pjT-lo
    const float* rowLo = sLo + m * 128;
    #pragma unroll 8
    for (int j4 = 0; j4 < 32; ++j4) {
        const float4 pv = *(const float4*)(rowLo + ((j4 ^ swz) << 2));
        const float4 av = *(const float4*)(adjr + (j4 << 2));   // uniform
        const f2 pv01 = {pv.x, pv.y}, pv23 = {pv.z, pv.w};
        const f2 av01 = {av.x, av.y}, av23 = {av.z, av.w};
        const f2 x01 = pim2 + pv01;                 // v_pk_add
        const f2 x23 = pim2 + pv23;
        const f2 g01 = nl2e2 * pv01 + npim2;        // v_pk_fma (contract)
        const f2 g23 = nl2e2 * pv23 + npim2;
        const float e0 = fast_exp2(g01.x), e1 = fast_exp2(g01.y);
        const float e2 = fast_exp2(g23.x), e3 = fast_exp2(g23.y);
        const f2 d01 = {e0 + 1.0f, e1 + 1.0f};
        const f2 d23 = {e2 + 1.0f, e3 + 1.0f};
        const float pA = d01.x * d01.y, pB = d23.x * d23.y;
        const float r  = fast_rcp(pA * pB);         // ONE rcp for 4 silus
        const f2 w01 = av01 * x01, w23 = av23 * x23;
        const f2 rd01 = d01.yx * (pB * r);          // 1/d0, 1/d1
        const f2 rd23 = d23.yx * (pA * r);          // 1/d2, 1/d3
        acc01 += w01 * rd01;                        // v_pk_fma
        acc23 += w23 * rd23;
    }

    __syncthreads();   // B2: all lo reads done
    stage_lin<8>(sLo, ws + WS_W2T, t);   // W2^T -> lo (under hi compute)

    // ---- Phase A, j in [128,256)
    const float* rowHi = sHi + m * 128;
    #pragma unroll 8
    for (int j4 = 0; j4 < 32; ++j4) {
        const float4 pv = *(const float4*)(rowHi + ((j4 ^ swz) << 2));
        const float4 av = *(const float4*)(adjr + 128 + (j4 << 2));
        const f2 pv01 = {pv.x, pv.y}, pv23 = {pv.z, pv.w};
        const f2 av01 = {av.x, av.y}, av23 = {av.z, av.w};
        const f2 x01 = pim2 + pv01;
        const f2 x23 = pim2 + pv23;
        const f2 g01 = nl2e2 * pv01 + npim2;
        const f2 g23 = nl2e2 * pv23 + npim2;
        const float e0 = fast_exp2(g01.x), e1 = fast_exp2(g01.y);
        const float e2 = fast_exp2(g23.x), e3 = fast_exp2(g23.y);
        const f2 d01 = {e0 + 1.0f, e1 + 1.0f};
        const f2 d23 = {e2 + 1.0f, e3 + 1.0f};
        const float pA = d01.x * d01.y, pB = d23.x * d23.y;
        const float r  = fast_rcp(pA * pB);
        const f2 w01 = av01 * x01, w23 = av23 * x23;
        const f2 rd01 = d01.yx * (pB * r);
        const f2 rd23 = d23.yx * (pA * r);
        acc01 += w01 * rd01;
        acc23 += w23 * rd23;
    }
    sS[(q << 7) + m] = ((acc01.x + acc01.y) + (acc23.x + acc23.y)) * inv;

    __syncthreads();   // B3: W2T staged, sS visible, hi reads done
    stage_lin<8>(sHi, ws + WS_WC1T, t);  // Wc1^T -> hi (under stage-1)

    // ================= Phase B: partial-split stages =====================
    // Stage partial macro-shape: thread (q,m) covers d in [32q, 32q+32),
    // weights: 8 owned b128 from WT[m]; vector operand: uniform b128.

    // ---- Stage 1 partials: magg = S@W2 (+ beta*b2 at combine)
    {
        const float* rw = sLo + m * 128;
        float p0 = 0.f, p1 = 0.f, p2 = 0.f, p3 = 0.f;
        #pragma unroll
        for (int i = 0; i < 8; ++i) {
            const int d4 = (q << 3) + i;
            const float4 wv4 = *(const float4*)(rw + ((d4 ^ swz) << 2));
            const float4 s0 = *(const float4*)(&sS[(0 << 7) + (d4 << 2)]);
            const float4 s1 = *(const float4*)(&sS[(1 << 7) + (d4 << 2)]);
            const float4 s2 = *(const float4*)(&sS[(2 << 7) + (d4 << 2)]);
            const float4 s3 = *(const float4*)(&sS[(3 << 7) + (d4 << 2)]);
            p0 = fmaf(s0.x, wv4.x, p0); p0 = fmaf(s0.y, wv4.y, p0);
            p0 = fmaf(s0.z, wv4.z, p0); p0 = fmaf(s0.w, wv4.w, p0);
            p1 = fmaf(s1.x, wv4.x, p1); p1 = fmaf(s1.y, wv4.y, p1);
            p1 = fmaf(s1.z, wv4.z, p1); p1 = fmaf(s1.w, wv4.w, p1);
            p2 = fmaf(s2.x, wv4.x, p2); p2 = fmaf(s2.y, wv4.y, p2);
            p2 = fmaf(s2.z, wv4.z, p2); p2 = fmaf(s2.w, wv4.w, p2);
            p3 = fmaf(s3.x, wv4.x, p3); p3 = fmaf(s3.y, wv4.y, p3);
            p3 = fmaf(s3.z, wv4.z, p3); p3 = fmaf(s3.w, wv4.w, p3);
        }
        float4 pv; pv.x = p0; pv.y = p1; pv.z = p2; pv.w = p3;
        *(float4*)&sP[m * 20 + (q << 2)] = pv;
    }
    __syncthreads();   // B4: sP visible; Wc1T staged (was in flight)

    // combine1 -> sB (magg row q)
    {
        const int base = m * 20 + q;
        const float mg = sP[base] + sP[base + 4] + sP[base + 8] + sP[base + 12]
                         + bet * b2k;
        sB[(q << 7) + m] = mg;
    }
    __syncthreads();   // B4b: sB visible
    stage_lin<8>(sLo, ws + WS_WC2T, t);  // Wc2^T -> lo (under stage-2)

    // ---- Stage 2 partials: t1 = silu(magg@Wc1 + bc1)
    {
        const float* rw = sHi + m * 128;
        float p0 = 0.f, p1 = 0.f, p2 = 0.f, p3 = 0.f;
        #pragma unroll
        for (int i = 0; i < 8; ++i) {
            const int d4 = (q << 3) + i;
            const float4 wv4 = *(const float4*)(rw + ((d4 ^ swz) << 2));
            const float4 s0 = *(const float4*)(&sB[(0 << 7) + (d4 << 2)]);
            const float4 s1 = *(const float4*)(&sB[(1 << 7) + (d4 << 2)]);
            const float4 s2 = *(const float4*)(&sB[(2 << 7) + (d4 << 2)]);
            const float4 s3 = *(const float4*)(&sB[(3 << 7) + (d4 << 2)]);
            p0 = fmaf(s0.x, wv4.x, p0); p0 = fmaf(s0.y, wv4.y, p0);
            p0 = fmaf(s0.z, wv4.z, p0); p0 = fmaf(s0.w, wv4.w, p0);
            p1 = fmaf(s1.x, wv4.x, p1); p1 = fmaf(s1.y, wv4.y, p1);
            p1 = fmaf(s1.z, wv4.z, p1); p1 = fmaf(s1.w, wv4.w, p1);
            p2 = fmaf(s2.x, wv4.x, p2); p2 = fmaf(s2.y, wv4.y, p2);
            p2 = fmaf(s2.z, wv4.z, p2); p2 = fmaf(s2.w, wv4.w, p2);
            p3 = fmaf(s3.x, wv4.x, p3); p3 = fmaf(s3.y, wv4.y, p3);
            p3 = fmaf(s3.z, wv4.z, p3); p3 = fmaf(s3.w, wv4.w, p3);
        }
        float4 pv; pv.x = p0; pv.y = p1; pv.z = p2; pv.w = p3;
        *(float4*)&sP[m * 20 + (q << 2)] = pv;
    }
    __syncthreads();   // B5: sP visible; Wc2T staged

    // combine2 -> sS (t1 row q); stage-1 sS readers finished before B4
    {
        const int base = m * 20 + q;
        const float tv = sP[base] + sP[base + 4] + sP[base + 8] + sP[base + 12]
                         + bc1k;
        sS[(q << 7) + m] = silu_f(tv);
    }
    __syncthreads();   // B5b: t1 visible

    // ---- Stage 3 partials: out = t1@Wc2 + bc2
    {
        const float* rw = sLo + m * 128;
        float p0 = 0.f, p1 = 0.f, p2 = 0.f, p3 = 0.f;
        #pragma unroll
        for (int i = 0; i < 8; ++i) {
            const int d4 = (q << 3) + i;
            const float4 wv4 = *(const float4*)(rw + ((d4 ^ swz) << 2));
            const float4 s0 = *(const float4*)(&sS[(0 << 7) + (d4 << 2)]);
            const float4 s1 = *(const float4*)(&sS[(1 << 7) + (d4 << 2)]);
            const float4 s2 = *(const float4*)(&sS[(2 << 7) + (d4 << 2)]);
            const float4 s3 = *(const float4*)(&sS[(3 << 7) + (d4 << 2)]);
            p0 = fmaf(s0.x, wv4.x, p0); p0 = fmaf(s0.y, wv4.y, p0);
            p0 = fmaf(s0.z, wv4.z, p0); p0 = fmaf(s0.w, wv4.w, p0);
            p1 = fmaf(s1.x, wv4.x, p1); p1 = fmaf(s1.y, wv4.y, p1);
            p1 = fmaf(s1.z, wv4.z, p1); p1 = fmaf(s1.w, wv4.w, p1);
            p2 = fmaf(s2.x, wv4.x, p2); p2 = fmaf(s2.y, wv4.y, p2);
            p2 = fmaf(s2.z, wv4.z, p2); p2 = fmaf(s2.w, wv4.w, p2);
            p3 = fmaf(s3.x, wv4.x, p3); p3 = fmaf(s3.y, wv4.y, p3);
            p3 = fmaf(s3.z, wv4.z, p3); p3 = fmaf(s3.w, wv4.w, p3);
        }
        float4 pv; pv.x = p0; pv.y = p1; pv.z = p2; pv.w = p3;
        *(float4*)&sP[m * 20 + (q << 2)] = pv;
    }
    __syncthreads();   // B6: sP visible

    // combine3 -> global store (coalesced: (row0+q)*CC + m == row0*CC + t)
    {
        const int base = m * 20 + q;
        const float ov = sP[base] + sP[base + 4] + sP[base + 8] + sP[base + 12]
                         + bc2k;
        out[(size_t)row0 * CC + t] = ov;
    }
}

extern "C" void kernel_launch(void* const* d_in, const int* in_sizes, int n_in,
                              void* d_out, int out_size, void* d_ws, size_t ws_size,
                              hipStream_t stream) {
    const float* h   = (const float*)d_in[0];
    const float* adj = (const float*)d_in[1];
    const float* W1a = (const float*)d_in[2];
    const float* W1b = (const float*)d_in[3];
    const float* b1  = (const float*)d_in[4];
    const float* W2  = (const float*)d_in[5];
    const float* b2  = (const float*)d_in[6];
    const float* Wc1 = (const float*)d_in[7];
    const float* bc1 = (const float*)d_in[8];
    const float* Wc2 = (const float*)d_in[9];
    const float* bc2 = (const float*)d_in[10];
    float* out = (float*)d_out;
    float* ws  = (float*)d_ws;

    k_proj<<<NBLK, TPB, 0, stream>>>(h, W1a, W1b, b1, W2, Wc1, Wc2, ws);
    k_msgout<<<NBLK, TPB, 0, stream>>>(adj, b2, bc1, bc2, ws, out);
}

// Round 9
// 94.922 us; speedup vs baseline: 1.0212x; 1.0212x over previous
//
#include <hip/hip_runtime.h>
#include <math.h>

// Shapes from reference: B=4, N=256, D=128, M=128, C=128
#define BB 4
#define NN 256
#define DD 128
#define MM 128
#define CC 128
#define ROWS (BB * NN)     // 1024
#define RPB 4              // rows per block
#define NBLK (ROWS / RPB)  // 256 blocks (== CU count, 1 block/CU)
#define TPB 512            // 8 waves

#define L2E 1.44269504088896340736f

// Workspace float offsets
#define WS_PIB   0          // pibias [1024][128]
#define WS_PJLO  131072     // pjT lo-half [4][128 m][128 j<128] (pre-swizzled)
#define WS_PJHI  196608     // pjT hi-half [4][128 m][128 j>=128]
#define WS_W2T   262144     // W2^T  [128][128] (pre-swizzled)
#define WS_WC1T  278528     // Wc1^T
#define WS_WC2T  294912     // Wc2^T

static __device__ __forceinline__ float fast_exp2(float x) {
#if __has_builtin(__builtin_amdgcn_exp2f)
    return __builtin_amdgcn_exp2f(x);
#else
    return __exp2f(x);
#endif
}

static __device__ __forceinline__ float fast_rcp(float x) {
#if __has_builtin(__builtin_amdgcn_rcpf)
    return __builtin_amdgcn_rcpf(x);
#else
    return 1.0f / x;
#endif
}

// silu(x) = x / (1 + exp(-x))
static __device__ __forceinline__ float silu_f(float x) {
    float e = fast_exp2(-L2E * x);
    return x * fast_rcp(1.0f + e);
}

#if __has_builtin(__builtin_amdgcn_global_load_lds)
#define HAS_GLDS 1
#define GLDS(gp, lp)                                                        \
    __builtin_amdgcn_global_load_lds(                                       \
        (const __attribute__((address_space(1))) void*)(gp),                \
        (__attribute__((address_space(3))) void*)(lp), 16, 0, 0)
#else
#define HAS_GLDS 0
#endif

// Linear burst stage: ITERS * 8 waves * 1KB chunks (source already laid out /
// pre-swizzled in global; LDS image == byte copy of source).
template <int ITERS>
static __device__ __forceinline__ void stage_lin(float* lds, const float* g,
                                                 int t) {
#if HAS_GLDS
    const int wv = t >> 6, lane = t & 63;
    #pragma unroll
    for (int i = 0; i < ITERS; ++i) {
        const int c = i * 8 + wv;              // 256-float chunk id
        GLDS(g + (size_t)c * 256 + lane * 4, lds + c * 256);
    }
#else
    #pragma unroll
    for (int i = 0; i < ITERS; ++i)
        ((float4*)lds)[i * TPB + t] = ((const float4*)g)[i * TPB + t];
#endif
}

// ---------------------------------------------------------------------------
// Kernel A: pibias = h@W1a + b1 ; pjT = (h@W1b)^T (pre-swizzled scatter).
// NO weight LDS: thread (m = t&127, X = mat, dup = d-half) reads each W value
// exactly once per CU via coalesced global b32 (L2-resident), accumulates
// partials for ALL 4 rows against broadcast h (2 KB LDS), then combines the
// two d-halves through a 20 KB sRed buffer. Blocks 0-11 also transpose
// W2/Wc1/Wc2 (pre-swizzled) into workspace for k_msgout Phase B.
// ---------------------------------------------------------------------------
__global__ __launch_bounds__(TPB) void k_proj(const float* __restrict__ h,
                                              const float* __restrict__ W1a,
                                              const float* __restrict__ W1b,
                                              const float* __restrict__ b1,
                                              const float* __restrict__ W2,
                                              const float* __restrict__ Wc1,
                                              const float* __restrict__ Wc2,
                                              float* __restrict__ ws) {
    __shared__ __align__(16) float sH[RPB * DD];   // 2 KB
    __shared__ __align__(16) float sRed[256 * 20]; // 20 KB: (X,m) rows of 20

    const int t = threadIdx.x;
    const int m   = t & 127;
    const int X   = (t >> 7) & 1;   // 0: W1a, 1: W1b   (wave-uniform)
    const int dup = t >> 8;         // d-half            (wave-uniform)
    const int row0 = blockIdx.x * RPB;

    sH[t] = h[(size_t)row0 * DD + t];
    const float* __restrict__ Wp = X ? W1b : W1a;
    const float bias = b1[m];
    __syncthreads();                 // sH visible

    const int d0 = dup * 64;
    float a0 = 0.f, a1 = 0.f, a2 = 0.f, a3 = 0.f;
    #pragma unroll 4
    for (int c = 0; c < 16; ++c) {
        const int d = d0 + c * 4;
        // coalesced global loads (L2-hit after first touch), 1 per value/CU
        const float w0 = Wp[(size_t)(d + 0) * MM + m];
        const float w1 = Wp[(size_t)(d + 1) * MM + m];
        const float w2 = Wp[(size_t)(d + 2) * MM + m];
        const float w3 = Wp[(size_t)(d + 3) * MM + m];
        // broadcast h chunks for all 4 rows (wave-uniform b128)
        const float4 h0 = *(const float4*)&sH[0 * DD + d];
        const float4 h1 = *(const float4*)&sH[1 * DD + d];
        const float4 h2 = *(const float4*)&sH[2 * DD + d];
        const float4 h3 = *(const float4*)&sH[3 * DD + d];
        a0 = fmaf(h0.x, w0, a0); a0 = fmaf(h0.y, w1, a0);
        a0 = fmaf(h0.z, w2, a0); a0 = fmaf(h0.w, w3, a0);
        a1 = fmaf(h1.x, w0, a1); a1 = fmaf(h1.y, w1, a1);
        a1 = fmaf(h1.z, w2, a1); a1 = fmaf(h1.w, w3, a1);
        a2 = fmaf(h2.x, w0, a2); a2 = fmaf(h2.y, w1, a2);
        a2 = fmaf(h2.z, w2, a2); a2 = fmaf(h2.w, w3, a2);
        a3 = fmaf(h3.x, w0, a3); a3 = fmaf(h3.y, w1, a3);
        a3 = fmaf(h3.z, w2, a3); a3 = fmaf(h3.w, w3, a3);
    }
    {
        float4 pv; pv.x = a0; pv.y = a1; pv.z = a2; pv.w = a3;
        *(float4*)&sRed[((X << 7) | m) * 20 + dup * 8] = pv;  // 16B-aligned
    }
    __syncthreads();                 // partials visible

    // Combine: this thread finishes rows q = 2*dup, 2*dup+1 for its (X,m).
    {
        const int base = ((X << 7) | m) * 20;
        #pragma unroll
        for (int k = 0; k < 2; ++k) {
            const int q = 2 * dup + k;
            const float v = sRed[base + q] + sRed[base + 8 + q];
            if (X == 0) {            // wave-uniform branch
                ws[WS_PIB + (size_t)(row0 + q) * MM + m] = v + bias;
            } else {
                // pjT pre-swizzled scatter: pjT[m][jloc], 16B slot ^= (m&7)
                const int b    = row0 >> 8;
                const int jloc = (row0 & 255) + q;
                const int half = jloc >> 7;
                const int jj   = jloc & 127;
                const int c16  = jj >> 2;
                const int off  = (half ? WS_PJHI : WS_PJLO) + b * 16384 +
                                 m * 128 + (((c16 ^ (m & 7)) << 2) | (jj & 3));
                ws[off] = v;
            }
        }
    }

    // Weight transposes (pre-swizzled): blocks 0-11, 32 d-rows each.
    if (blockIdx.x < 12) {
        const int blk = blockIdx.x;
        const int qq = t >> 7;       // 0..3
        const float* Wsrc = (blk < 4) ? W2 : (blk < 8) ? Wc1 : Wc2;
        float* Wdst = ws + ((blk < 4) ? WS_W2T : (blk < 8) ? WS_WC1T : WS_WC2T);
        const int d0t = (blk & 3) * 32;
        const int k = m;
        #pragma unroll
        for (int i = 0; i < 8; ++i) {
            const int d = d0t + (qq << 3) + i;
            const float v = Wsrc[(size_t)d * 128 + k];   // coalesced over k
            Wdst[k * 128 + ((((d >> 2) ^ (k & 7)) << 2) | (d & 3))] = v;
        }
    }
}

// ---------------------------------------------------------------------------
// Kernel B: fused msg + output head. 256 blocks x 512 threads, 4 rows/block.
// Phase A: swizzled b128 pjT rows + uniform adj, FOUR independent
// accumulators (breaks the 256-deep serial fmac chain -- the last remaining
// dependency-latency bottleneck at 2 waves/SIMD).
// Phase B partial-split: thread (q,m) reads only WT[m][32q..32q+32) (8 b128 --
// each weight value once per CU), computes partials for ALL 4 output rows,
// combines via sP. Weights staged under the previous phase's compute.
// ---------------------------------------------------------------------------
__global__ __launch_bounds__(TPB) void k_msgout(const float* __restrict__ adj,
                                                const float* __restrict__ b2,
                                                const float* __restrict__ bc1,
                                                const float* __restrict__ bc2,
                                                const float* __restrict__ ws,
                                                float* __restrict__ out) {
    __shared__ __align__(16) float sLo[16384];    // 64 KB: pjT lo / W2T / Wc2T
    __shared__ __align__(16) float sHi[16384];    // 64 KB: pjT hi / Wc1T
    __shared__ __align__(16) float sS[RPB * MM];  // S rows, later t1
    __shared__ __align__(16) float sB[RPB * MM];  // magg
    __shared__ __align__(16) float sP[128 * 20];  // 10 KB: stage partials
    __shared__ float sWr0[8], sWr1[8];

    const int t = threadIdx.x;
    const int blk = blockIdx.x;        // 256 blocks
    const int b = blk >> 6;            // batch
    const int i0 = (blk & 63) * RPB;   // first row (batch-local)
    const int row0 = b * NN + i0;

    const int m = t & 127;
    const int q = t >> 7;              // row within block (uniform per wave)
    const int w = t >> 6;              // wave id
    const int swz = m & 7;

    // ---- issue pjT staging (128 KB total, pre-swizzled source -> linear)
    stage_lin<8>(sLo, ws + WS_PJLO + b * 16384, t);
    stage_lin<8>(sHi, ws + WS_PJHI + b * 16384, t);

    // ---- early loads (overlap with staging)
    const float pim  = ws[WS_PIB + (size_t)row0 * MM + t];  // pibias[row0+q][m]
    const float b2k  = b2[m];
    const float bc1k = bc1[m];
    const float bc2k = bc2[m];

    // adj row sums via coalesced vector loads + wave shuffle
    const float* arow = adj + (size_t)row0 * NN;
    const float a0v = arow[t];          // rows 0/1
    const float a1v = arow[t + TPB];    // rows 2/3
    float v0 = a0v, v1 = a1v;
    #pragma unroll
    for (int off = 32; off > 0; off >>= 1) {
        v0 += __shfl_xor(v0, off, 64);
        v1 += __shfl_xor(v1, off, 64);
    }
    if ((t & 63) == 0) { sWr0[w] = v0; sWr1[w] = v1; }

    // wave-uniform adj row pointer (scalarized)
    const int srow = __builtin_amdgcn_readfirstlane(row0 + q);
    const float* __restrict__ adjr = adj + (size_t)srow * NN;

    __syncthreads();   // B1: pjT staged, sWr visible

    float A;
    {
        const int base = (q & 1) * 4;
        A = (q < 2) ? (sWr0[base] + sWr0[base + 1] + sWr0[base + 2] + sWr0[base + 3])
                    : (sWr1[base] + sWr1[base + 1] + sWr1[base + 2] + sWr1[base + 3]);
    }
    const float aii = adjr[srow & 255];     // diagonal (uniform scalar load)
    const float inv = 1.0f / fmaxf(A, 1.0f);
    const float bet = (A - aii) * inv;
    const float npim = -L2E * pim;

    // Diagonal correction (subtract instead of zeroing adj)
    float dcorr;
    {
        const int iloc = i0 + q;
        const int jj = iloc & 127;
        const float* base = (iloc < 128) ? sLo : sHi;
        const float pjd = base[m * 128 + ((((jj >> 2) ^ swz) << 2) | (jj & 3))];
        dcorr = -aii * silu_f(pim + pjd);
    }

    // ---- Phase A: 4 INDEPENDENT accumulators (no serial fmac chain)
    float ac0 = dcorr, ac1 = 0.f, ac2 = 0.f, ac3 = 0.f;

    // j in [0,128): swizzled b128 rows of pjT-lo
    const float* rowLo = sLo + m * 128;
    #pragma unroll 8
    for (int j4 = 0; j4 < 32; ++j4) {
        const float4 pv = *(const float4*)(rowLo + ((j4 ^ swz) << 2));
        const float4 av = *(const float4*)(adjr + (j4 << 2));   // uniform
        const float x0 = pim + pv.x, x1 = pim + pv.y;
        const float x2 = pim + pv.z, x3 = pim + pv.w;
        const float e0 = fast_exp2(fmaf(-L2E, pv.x, npim));
        const float e1 = fast_exp2(fmaf(-L2E, pv.y, npim));
        const float e2 = fast_exp2(fmaf(-L2E, pv.z, npim));
        const float e3 = fast_exp2(fmaf(-L2E, pv.w, npim));
        const float d0 = 1.0f + e0, d1 = 1.0f + e1;
        const float d2 = 1.0f + e2, d3 = 1.0f + e3;
        const float r01 = fast_rcp(d0 * d1), r23 = fast_rcp(d2 * d3);
        ac0 = fmaf(av.x * x0, r01 * d1, ac0);
        ac1 = fmaf(av.y * x1, r01 * d0, ac1);
        ac2 = fmaf(av.z * x2, r23 * d3, ac2);
        ac3 = fmaf(av.w * x3, r23 * d2, ac3);
    }

    __syncthreads();   // B2: all lo reads done
    stage_lin<8>(sLo, ws + WS_W2T, t);   // W2^T -> lo (under hi compute)

    // ---- Phase A, j in [128,256)
    const float* rowHi = sHi + m * 128;
    #pragma unroll 8
    for (int j4 = 0; j4 < 32; ++j4) {
        const float4 pv = *(const float4*)(rowHi + ((j4 ^ swz) << 2));
        const float4 av = *(const float4*)(adjr + 128 + (j4 << 2));
        const float x0 = pim + pv.x, x1 = pim + pv.y;
        const float x2 = pim + pv.z, x3 = pim + pv.w;
        const float e0 = fast_exp2(fmaf(-L2E, pv.x, npim));
        const float e1 = fast_exp2(fmaf(-L2E, pv.y, npim));
        const float e2 = fast_exp2(fmaf(-L2E, pv.z, npim));
        const float e3 = fast_exp2(fmaf(-L2E, pv.w, npim));
        const float d0 = 1.0f + e0, d1 = 1.0f + e1;
        const float d2 = 1.0f + e2, d3 = 1.0f + e3;
        const float r01 = fast_rcp(d0 * d1), r23 = fast_rcp(d2 * d3);
        ac0 = fmaf(av.x * x0, r01 * d1, ac0);
        ac1 = fmaf(av.y * x1, r01 * d0, ac1);
        ac2 = fmaf(av.z * x2, r23 * d3, ac2);
        ac3 = fmaf(av.w * x3, r23 * d2, ac3);
    }
    sS[(q << 7) + m] = ((ac0 + ac1) + (ac2 + ac3)) * inv;

    __syncthreads();   // B3: W2T staged, sS visible, hi reads done
    stage_lin<8>(sHi, ws + WS_WC1T, t);  // Wc1^T -> hi (under stage-1)

    // ================= Phase B: partial-split stages =====================
    // Stage partial macro-shape: thread (q,m) covers d in [32q, 32q+32),
    // weights: 8 owned b128 from WT[m]; vector operand: uniform b128.

    // ---- Stage 1 partials: magg = S@W2 (+ beta*b2 at combine)
    {
        const float* rw = sLo + m * 128;
        float p0 = 0.f, p1 = 0.f, p2 = 0.f, p3 = 0.f;
        #pragma unroll
        for (int i = 0; i < 8; ++i) {
            const int d4 = (q << 3) + i;
            const float4 wv4 = *(const float4*)(rw + ((d4 ^ swz) << 2));
            const float4 s0 = *(const float4*)(&sS[(0 << 7) + (d4 << 2)]);
            const float4 s1 = *(const float4*)(&sS[(1 << 7) + (d4 << 2)]);
            const float4 s2 = *(const float4*)(&sS[(2 << 7) + (d4 << 2)]);
            const float4 s3 = *(const float4*)(&sS[(3 << 7) + (d4 << 2)]);
            p0 = fmaf(s0.x, wv4.x, p0); p0 = fmaf(s0.y, wv4.y, p0);
            p0 = fmaf(s0.z, wv4.z, p0); p0 = fmaf(s0.w, wv4.w, p0);
            p1 = fmaf(s1.x, wv4.x, p1); p1 = fmaf(s1.y, wv4.y, p1);
            p1 = fmaf(s1.z, wv4.z, p1); p1 = fmaf(s1.w, wv4.w, p1);
            p2 = fmaf(s2.x, wv4.x, p2); p2 = fmaf(s2.y, wv4.y, p2);
            p2 = fmaf(s2.z, wv4.z, p2); p2 = fmaf(s2.w, wv4.w, p2);
            p3 = fmaf(s3.x, wv4.x, p3); p3 = fmaf(s3.y, wv4.y, p3);
            p3 = fmaf(s3.z, wv4.z, p3); p3 = fmaf(s3.w, wv4.w, p3);
        }
        float4 pv; pv.x = p0; pv.y = p1; pv.z = p2; pv.w = p3;
        *(float4*)&sP[m * 20 + (q << 2)] = pv;
    }
    __syncthreads();   // B4: sP visible; Wc1T staged (was in flight)

    // combine1 -> sB (magg row q)
    {
        const int base = m * 20 + q;
        const float mg = sP[base] + sP[base + 4] + sP[base + 8] + sP[base + 12]
                         + bet * b2k;
        sB[(q << 7) + m] = mg;
    }
    __syncthreads();   // B4b: sB visible
    stage_lin<8>(sLo, ws + WS_WC2T, t);  // Wc2^T -> lo (under stage-2)

    // ---- Stage 2 partials: t1 = silu(magg@Wc1 + bc1)
    {
        const float* rw = sHi + m * 128;
        float p0 = 0.f, p1 = 0.f, p2 = 0.f, p3 = 0.f;
        #pragma unroll
        for (int i = 0; i < 8; ++i) {
            const int d4 = (q << 3) + i;
            const float4 wv4 = *(const float4*)(rw + ((d4 ^ swz) << 2));
            const float4 s0 = *(const float4*)(&sB[(0 << 7) + (d4 << 2)]);
            const float4 s1 = *(const float4*)(&sB[(1 << 7) + (d4 << 2)]);
            const float4 s2 = *(const float4*)(&sB[(2 << 7) + (d4 << 2)]);
            const float4 s3 = *(const float4*)(&sB[(3 << 7) + (d4 << 2)]);
            p0 = fmaf(s0.x, wv4.x, p0); p0 = fmaf(s0.y, wv4.y, p0);
            p0 = fmaf(s0.z, wv4.z, p0); p0 = fmaf(s0.w, wv4.w, p0);
            p1 = fmaf(s1.x, wv4.x, p1); p1 = fmaf(s1.y, wv4.y, p1);
            p1 = fmaf(s1.z, wv4.z, p1); p1 = fmaf(s1.w, wv4.w, p1);
            p2 = fmaf(s2.x, wv4.x, p2); p2 = fmaf(s2.y, wv4.y, p2);
            p2 = fmaf(s2.z, wv4.z, p2); p2 = fmaf(s2.w, wv4.w, p2);
            p3 = fmaf(s3.x, wv4.x, p3); p3 = fmaf(s3.y, wv4.y, p3);
            p3 = fmaf(s3.z, wv4.z, p3); p3 = fmaf(s3.w, wv4.w, p3);
        }
        float4 pv; pv.x = p0; pv.y = p1; pv.z = p2; pv.w = p3;
        *(float4*)&sP[m * 20 + (q << 2)] = pv;
    }
    __syncthreads();   // B5: sP visible; Wc2T staged

    // combine2 -> sS (t1 row q); stage-1 sS readers finished before B4
    {
        const int base = m * 20 + q;
        const float tv = sP[base] + sP[base + 4] + sP[base + 8] + sP[base + 12]
                         + bc1k;
        sS[(q << 7) + m] = silu_f(tv);
    }
    __syncthreads();   // B5b: t1 visible

    // ---- Stage 3 partials: out = t1@Wc2 + bc2
    {
        const float* rw = sLo + m * 128;
        float p0 = 0.f, p1 = 0.f, p2 = 0.f, p3 = 0.f;
        #pragma unroll
        for (int i = 0; i < 8; ++i) {
            const int d4 = (q << 3) + i;
            const float4 wv4 = *(const float4*)(rw + ((d4 ^ swz) << 2));
            const float4 s0 = *(const float4*)(&sS[(0 << 7) + (d4 << 2)]);
            const float4 s1 = *(const float4*)(&sS[(1 << 7) + (d4 << 2)]);
            const float4 s2 = *(const float4*)(&sS[(2 << 7) + (d4 << 2)]);
            const float4 s3 = *(const float4*)(&sS[(3 << 7) + (d4 << 2)]);
            p0 = fmaf(s0.x, wv4.x, p0); p0 = fmaf(s0.y, wv4.y, p0);
            p0 = fmaf(s0.z, wv4.z, p0); p0 = fmaf(s0.w, wv4.w, p0);
            p1 = fmaf(s1.x, wv4.x, p1); p1 = fmaf(s1.y, wv4.y, p1);
            p1 = fmaf(s1.z, wv4.z, p1); p1 = fmaf(s1.w, wv4.w, p1);
            p2 = fmaf(s2.x, wv4.x, p2); p2 = fmaf(s2.y, wv4.y, p2);
            p2 = fmaf(s2.z, wv4.z, p2); p2 = fmaf(s2.w, wv4.w, p2);
            p3 = fmaf(s3.x, wv4.x, p3); p3 = fmaf(s3.y, wv4.y, p3);
            p3 = fmaf(s3.z, wv4.z, p3); p3 = fmaf(s3.w, wv4.w, p3);
        }
        float4 pv; pv.x = p0; pv.y = p1; pv.z = p2; pv.w = p3;
        *(float4*)&sP[m * 20 + (q << 2)] = pv;
    }
    __syncthreads();   // B6: sP visible

    // combine3 -> global store (coalesced: (row0+q)*CC + m == row0*CC + t)
    {
        const int base = m * 20 + q;
        const float ov = sP[base] + sP[base + 4] + sP[base + 8] + sP[base + 12]
                         + bc2k;
        out[(size_t)row0 * CC + t] = ov;
    }
}

extern "C" void kernel_launch(void* const* d_in, const int* in_sizes, int n_in,
                              void* d_out, int out_size, void* d_ws, size_t ws_size,
                              hipStream_t stream) {
    const float* h   = (const float*)d_in[0];
    const float* adj = (const float*)d_in[1];
    const float* W1a = (const float*)d_in[2];
    const float* W1b = (const float*)d_in[3];
    const float* b1  = (const float*)d_in[4];
    const float* W2  = (const float*)d_in[5];
    const float* b2  = (const float*)d_in[6];
    const float* Wc1 = (const float*)d_in[7];
    const float* bc1 = (const float*)d_in[8];
    const float* Wc2 = (const float*)d_in[9];
    const float* bc2 = (const float*)d_in[10];
    float* out = (float*)d_out;
    float* ws  = (float*)d_ws;

    k_proj<<<NBLK, TPB, 0, stream>>>(h, W1a, W1b, b1, W2, Wc1, Wc2, ws);
    k_msgout<<<NBLK, TPB, 0, stream>>>(adj, b2, bc1, bc2, ws, out);
}